// Round 10
// baseline (842.043 us; speedup 1.0000x reference)
//
#include <hip/hip_runtime.h>
#include <stdint.h>

typedef unsigned short u16;
typedef unsigned int   u32;
typedef signed char    s8;

typedef __bf16 bf16x8 __attribute__((ext_vector_type(8)));
typedef float  f32x4  __attribute__((ext_vector_type(4)));
typedef int    i32x4  __attribute__((ext_vector_type(4)));

// Sizes: B=256, T=64, H=256, M2=512, gates=1024
// ws layout (bytes):
//   WattQ  i8 B-frag [nt<16][kt<8][lane<64][i<16] : off 0,      sz 131072
//   WencB  bf16 B-frag (K=32 tiles)               : off 131072, sz 262144
//   WhhQ   i8 B-frag [j][nt<64][kt<4][lane][i]    : off 393216, sz 524288
//   beff   f32 [256]                              : off 917504
//   gbias  f32 [2][1024]                          : off 918528
//   cmAtt  f32 [256]                              : off 926720
//   cmWhh  f32 [2048]                             : off 927744
//   fcE    f32 [515]                              : off 935936

__device__ __forceinline__ float bf2f(u16 v){ return __uint_as_float(((u32)v) << 16); }
__device__ __forceinline__ u16 f2bf(float f){
  u32 u = __float_as_uint(f);
  u += 0x7fffu + ((u >> 16) & 1u);
  return (u16)(u >> 16);
}
__device__ __forceinline__ u32 pk2(float a, float b){
  return (u32)f2bf(a) | (((u32)f2bf(b)) << 16);
}
__device__ __forceinline__ float wave_sum(float v){
  #pragma unroll
  for (int o = 32; o > 0; o >>= 1) v += __shfl_xor(v, o, 64);
  return v;
}
__device__ __forceinline__ float tanh_fast(float x){
  float e = __builtin_amdgcn_exp2f(x * 2.88539008178f); // 2*log2(e)
  return 1.0f - 2.0f * __builtin_amdgcn_rcpf(1.0f + e);
}
__device__ __forceinline__ float sigm(float x){
  float e = __builtin_amdgcn_exp2f(-x * 1.44269504089f);
  return __builtin_amdgcn_rcpf(1.0f + e);
}
__device__ __forceinline__ f32x4 mfma16(bf16x8 a, bf16x8 b, f32x4 c){
  return __builtin_amdgcn_mfma_f32_16x16x32_bf16(a, b, c, 0, 0, 0);
}
__device__ __forceinline__ i32x4 mfma_i8(uint4 a, uint4 b, i32x4 c){
  return __builtin_amdgcn_mfma_i32_16x16x64_i8(
      __builtin_bit_cast(i32x4, a), __builtin_bit_cast(i32x4, b), c, 0, 0, 0);
}
// bf16 B-frag index (16x16x32): lane = ((k>>3)&3)*16 + (n&15), i = k&7
__device__ __forceinline__ size_t bfrag_idx(int n, int k, int KS){
  return ((size_t)((n >> 4) * KS + (k >> 5)) * 64 + ((k >> 3) & 3) * 16 + (n & 15)) * 8 + (k & 7);
}
// i8 B-frag index (16x16x64): lane = ((k>>4)&3)*16 + (n&15), i = k&15; KS = K/64
__device__ __forceinline__ size_t bq_idx(int n, int k, int KS){
  return ((size_t)((n >> 4) * KS + (k >> 6)) * 64 + ((k >> 4) & 3) * 16 + (n & 15)) * 16 + (k & 15);
}

#define ETS 258   // encT padded stride (u16); dword stride 129 (odd) -> conflict-free

// ---------------- prep kernels (R7, verified) ----------------

__global__ __launch_bounds__(256) void prep_attn(
    const float* __restrict__ w1, const float* __restrict__ b1,
    const float* __restrict__ w2, const float* __restrict__ b2,
    s8* __restrict__ WattQ, u16* __restrict__ WencB,
    float* __restrict__ beff, float* __restrict__ cmAtt)
{
  const int h = blockIdx.x, tid = threadIdx.x;
  __shared__ float w2row[256];
  __shared__ float red[256];
  w2row[tid] = w2[h * 256 + tid];
  __syncthreads();
  float acc0 = 0.f, acc1 = 0.f, acc2 = 0.f, acc3 = 0.f;
  for (int m = 0; m < 256; ++m){
    const float wm = w2row[m];
    const float* r = w1 + m * 1024 + tid;
    acc0 += wm * r[0];
    acc1 += wm * r[256];
    acc2 += wm * r[512];
    acc3 += wm * r[768];
  }
  WencB[bfrag_idx(h, tid,       16)] = f2bf(acc2);
  WencB[bfrag_idx(h, tid + 256, 16)] = f2bf(acc3);
  red[tid] = fmaxf(fabsf(acc0), fabsf(acc1));
  __syncthreads();
  for (int s = 128; s > 0; s >>= 1){
    if (tid < s) red[tid] = fmaxf(red[tid], red[tid + s]);
    __syncthreads();
  }
  const float cm = red[0] + 1e-30f;
  const float s127 = 127.f / cm;
  WattQ[bq_idx(h, tid,       8)] = (s8)rintf(acc0 * s127);
  WattQ[bq_idx(h, tid + 256, 8)] = (s8)rintf(acc1 * s127);
  if (tid == 0) cmAtt[h] = cm;
  __syncthreads();
  red[tid] = w2row[tid] * b1[tid];
  __syncthreads();
  for (int s = 128; s > 0; s >>= 1){
    if (tid < s) red[tid] += red[tid + s];
    __syncthreads();
  }
  if (tid == 0) beff[h] = red[0] + b2[h];
}

__global__ __launch_bounds__(256) void prep_whh_i8(
    const float* __restrict__ whhf, const float* __restrict__ whhb,
    const float* __restrict__ bihf, const float* __restrict__ bhhf,
    const float* __restrict__ bihb, const float* __restrict__ bhhb,
    s8* __restrict__ WhhQ, float* __restrict__ gbias, float* __restrict__ cmWhh)
{
  const int col = blockIdx.x * 256 + threadIdx.x;  // < 2048
  const int j = col >> 10, n = col & 1023;
  const float* w = j ? whhb : whhf;
  const float* r = w + n * 256;
  float cm = 0.f;
  for (int k = 0; k < 256; ++k) cm = fmaxf(cm, fabsf(r[k]));
  cm += 1e-30f;
  cmWhh[col] = cm;
  const float s127 = 127.f / cm;
  s8* dst = WhhQ + (size_t)j * 262144;
  for (int k = 0; k < 256; ++k)
    dst[bq_idx(n, k, 4)] = (s8)rintf(r[k] * s127);
  gbias[col] = j ? (bihb[n] + bhhb[n]) : (bihf[n] + bhhf[n]);
}

__global__ __launch_bounds__(256) void prep_fc(
    const float* __restrict__ fcw1, const float* __restrict__ fcb1,
    const float* __restrict__ fcw2, const float* __restrict__ fcb2,
    float* __restrict__ fcE)
{
  const int tid = threadIdx.x;
  __shared__ float w2s[256];
  __shared__ float red[256];
  w2s[tid] = fcw2[tid];
  __syncthreads();
  for (int m = tid; m < 514; m += 256){
    float a = 0.f;
    for (int hh = 0; hh < 256; ++hh) a += w2s[hh] * fcw1[hh * 514 + m];
    fcE[m] = a;
  }
  red[tid] = w2s[tid] * fcb1[tid];
  __syncthreads();
  for (int s = 128; s > 0; s >>= 1){
    if (tid < s) red[tid] += red[tid + s];
    __syncthreads();
  }
  if (tid == 0) fcE[514] = red[0] + fcb2[0];
}

// ---- gate tiles: nt in [nt0, ntEnd), single j. Quad-batched loads (16 in
// flight) then pair then single. Called ONLY in phase B where pbH/pbC are
// dead -> no register spill. ----
__device__ __forceinline__ void gate_tiles(int nt0, int ntEnd,
    const uint4 (&aG)[4], const s8* __restrict__ wbJ, int* __restrict__ preSj,
    int lane, int col)
{
  int nt = nt0;
  #pragma unroll 1
  for (; nt + 3 < ntEnd; nt += 4){
    uint4 gb[16];
    #pragma unroll
    for (int tt = 0; tt < 4; ++tt)
      #pragma unroll
      for (int kt = 0; kt < 4; ++kt)
        gb[tt * 4 + kt] = *(const uint4*)(wbJ + ((((nt + tt) * 4 + kt) * 64 + lane) << 4));
    i32x4 g0 = (i32x4){0,0,0,0}, g1 = (i32x4){0,0,0,0};
    i32x4 g2 = (i32x4){0,0,0,0}, g3 = (i32x4){0,0,0,0};
    #pragma unroll
    for (int kt = 0; kt < 4; ++kt){
      g0 = mfma_i8(aG[kt], gb[kt],      g0);
      g1 = mfma_i8(aG[kt], gb[4 + kt],  g1);
      g2 = mfma_i8(aG[kt], gb[8 + kt],  g2);
      g3 = mfma_i8(aG[kt], gb[12 + kt], g3);
    }
    if (lane < 16){
      preSj[nt * 16 + col]       = g0[0];
      preSj[(nt + 1) * 16 + col] = g1[0];
      preSj[(nt + 2) * 16 + col] = g2[0];
      preSj[(nt + 3) * 16 + col] = g3[0];
    }
  }
  #pragma unroll 1
  for (; nt + 1 < ntEnd; nt += 2){
    uint4 gb[8];
    #pragma unroll
    for (int kt = 0; kt < 4; ++kt){
      gb[kt]     = *(const uint4*)(wbJ + (((nt * 4 + kt) * 64 + lane) << 4));
      gb[4 + kt] = *(const uint4*)(wbJ + ((((nt + 1) * 4 + kt) * 64 + lane) << 4));
    }
    i32x4 g0 = (i32x4){0,0,0,0}, g1 = (i32x4){0,0,0,0};
    #pragma unroll
    for (int kt = 0; kt < 4; ++kt){
      g0 = mfma_i8(aG[kt], gb[kt],     g0);
      g1 = mfma_i8(aG[kt], gb[4 + kt], g1);
    }
    if (lane < 16){
      preSj[nt * 16 + col]       = g0[0];
      preSj[(nt + 1) * 16 + col] = g1[0];
    }
  }
  if (nt < ntEnd){
    i32x4 g0 = (i32x4){0,0,0,0};
    #pragma unroll
    for (int kt = 0; kt < 4; ++kt){
      const uint4 b0 = *(const uint4*)(wbJ + (((nt * 4 + kt) * 64 + lane) << 4));
      g0 = mfma_i8(aG[kt], b0, g0);
    }
    if (lane < 16) preSj[nt * 16 + col] = g0[0];
  }
}

// ---------------- main kernel: 1024 threads (16 waves) per batch element ----------------
__global__ __launch_bounds__(1024, 4) void decoder_main(
    const float* __restrict__ enc,   const float* __restrict__ yhist,
    const float* __restrict__ speed, const float* __restrict__ h0,
    const float* __restrict__ c0,    const float* __restrict__ aw3,
    const float* __restrict__ wihf,  const float* __restrict__ wihb,
    const float* __restrict__ fcfw,  const float* __restrict__ fcfb,
    const s8* __restrict__ WattQ,    const u16* __restrict__ WencB,
    const s8* __restrict__ WhhQ,     const float* __restrict__ beff,
    const float* __restrict__ gbias, const float* __restrict__ cmAtt,
    const float* __restrict__ cmWhh, const float* __restrict__ fcE,
    float* __restrict__ out)
{
  const int b = blockIdx.x, tid = threadIdx.x;
  const int lane = tid & 63, wv = tid >> 6;   // wv < 16
  const int q = lane >> 4, col = lane & 15;

  __shared__ float hcin[2][512];               // fp32 state: [j][k<256]=h, [256..512)=c
  __shared__ alignas(16) s8 hQ[2][256];        // int8 quantized h (per-step)
  __shared__ alignas(16) s8 cQ[2][256];        // int8 quantized c
  __shared__ alignas(16) u16 encT[64 * ETS];   // enc attention term, padded stride
  __shared__ alignas(16) u16 encLDS[64 * 512]; // raw enc (bf16), prologue+epilogue
  __shared__ alignas(16) float hcpP[512];      // attention projection, [h][v] pairs
  __shared__ alignas(16) float w3L[256];
  __shared__ float w1s[256];                   // cmAtt/127^2
  __shared__ float encFE[64];
  __shared__ float attwS[64];
  __shared__ float attw_acc[64];
  __shared__ float scp[4][64];                 // P2 h-quarter partials
  __shared__ float red[16];
  __shared__ float redH[8], redC[8];           // per-wave |h|,|c| maxima (waves 0..7)
  __shared__ float mS[4];                      // m_h[0..1], m_c[0..1]
  __shared__ int   preSi[2][1024];             // raw i32 gate dots from MFMA
  __shared__ float yS[64], sS[64];
  __shared__ float ctx[512];

  // ---- init state + |h0|,|c0| wave maxima ----
  if (tid < 512){
    const int j = tid >> 8, p = tid & 255;
    const float hv = h0[j * 65536 + b * 256 + p];
    const float cv = c0[j * 65536 + b * 256 + p];
    hcin[j][p]       = hv;
    hcin[j][256 + p] = cv;
    float ah = fabsf(hv), ac = fabsf(cv);
    #pragma unroll
    for (int o = 32; o > 0; o >>= 1){
      ah = fmaxf(ah, __shfl_xor(ah, o, 64));
      ac = fmaxf(ac, __shfl_xor(ac, o, 64));
    }
    if (lane == 0){ redH[wv] = ah; redC[wv] = ac; }
  }
  if (tid < 64){
    attw_acc[tid] = 0.f;
    yS[tid] = yhist[b * 64 + tid];
    sS[tid] = speed[b * 64 + tid];
  }
  if (tid < 256){
    w3L[tid] = aw3[tid];
    w1s[tid] = cmAtt[tid] * (1.f / 16129.f);
  }

  const float* encB = enc + (size_t)b * 32768;

  // ---- prologue: encT[s][h] = enc[b,s,:].WencB + beff (bf16 MFMA GEMM, M=64,K=512,N=256)
  {
    const int mt = wv >> 2, g = wv & 3;
    const int s = mt * 16 + col;
    f32x4 acc[4];
    #pragma unroll
    for (int tt = 0; tt < 4; ++tt) acc[tt] = (f32x4){0.f, 0.f, 0.f, 0.f};
    #pragma unroll 1
    for (int ks = 0; ks < 16; ++ks){
      const float* ap = encB + s * 512 + ks * 32 + q * 8;
      const float4 e0 = *(const float4*)ap;
      const float4 e1 = *(const float4*)(ap + 4);
      uint4 af;
      af.x = pk2(e0.x, e0.y); af.y = pk2(e0.z, e0.w);
      af.z = pk2(e1.x, e1.y); af.w = pk2(e1.z, e1.w);
      if (g == 0) *(uint4*)&encLDS[s * 512 + ks * 32 + q * 8] = af;
      const bf16x8 a = __builtin_bit_cast(bf16x8, af);
      #pragma unroll
      for (int tt = 0; tt < 4; ++tt){
        const int nt = g * 4 + tt;
        const uint4 bw = *(const uint4*)(WencB + (((nt * 16 + ks) * 64 + lane) << 3));
        acc[tt] = mfma16(a, __builtin_bit_cast(bf16x8, bw), acc[tt]);
      }
    }
    #pragma unroll
    for (int tt = 0; tt < 4; ++tt){
      const int nt = g * 4 + tt;
      const float bv = beff[nt * 16 + col];
      #pragma unroll
      for (int r = 0; r < 4; ++r)
        encT[(mt * 16 + q * 4 + r) * ETS + nt * 16 + col] = f2bf(acc[tt][r] + bv);
    }
  }
  __syncthreads();  // encLDS ready

  // ---- encFE[s] = sum_m bf16(enc[s,m]) * fcE[m]
  {
    const float4 f0 = *(const float4*)(fcE + lane * 8);
    const float4 f1 = *(const float4*)(fcE + lane * 8 + 4);
    #pragma unroll
    for (int r = 0; r < 4; ++r){
      const int s = wv * 4 + r;
      const uint4 ev = *(const uint4*)&encLDS[s * 512 + lane * 8];
      float p = bf2f(ev.x & 0xffff) * f0.x + bf2f(ev.x >> 16) * f0.y
              + bf2f(ev.y & 0xffff) * f0.z + bf2f(ev.y >> 16) * f0.w
              + bf2f(ev.z & 0xffff) * f1.x + bf2f(ev.z >> 16) * f1.y
              + bf2f(ev.w & 0xffff) * f1.z + bf2f(ev.w >> 16) * f1.w;
      p = wave_sum(p);
      if (lane == 0) encFE[s] = p;
    }
  }

  // ---- per-thread constants ----
  const int jj = (tid >> 8) & 1, pp = tid & 255;   // update-phase ids (tid<512)
  const float* wihJ = jj ? wihb : wihf;
  const float wvg_i = wihJ[pp], wvg_f = wihJ[pp + 256], wvg_g = wihJ[pp + 512], wvg_o = wihJ[pp + 768];
  const float gb_i = gbias[jj * 1024 + pp],       gb_f = gbias[jj * 1024 + pp + 256];
  const float gb_g = gbias[jj * 1024 + pp + 512], gb_o = gbias[jj * 1024 + pp + 768];
  const float c4i = cmWhh[jj * 1024 + pp]       * (1.f / 16129.f);
  const float c4f = cmWhh[jj * 1024 + pp + 256] * (1.f / 16129.f);
  const float c4g = cmWhh[jj * 1024 + pp + 512] * (1.f / 16129.f);
  const float c4o = cmWhh[jj * 1024 + pp + 768] * (1.f / 16129.f);
  const float feY = fcE[512], feS = fcE[513], feB = fcE[514];

  // ---- gate tile assignment: tile u = j*64+nt, u<128; ALL in phase B ----
  // waves 0-3: none (they run P2); waves 4-11: 11 tiles; waves 12-15: 10.
  int gstart, gcnt;
  if (wv < 4)       { gstart = 0;                  gcnt = 0;  }
  else if (wv < 12) { gstart = (wv - 4) * 11;      gcnt = 11; }
  else              { gstart = 88 + (wv - 12) * 10; gcnt = 10; }

  __syncthreads();  // init/encFE visible

  // ---- 64 sequential decode steps ----
  #pragma unroll 1
  for (int t = 0; t < 64; ++t){
    // ---- prefetch P1 B-frags (state-independent; overlap quantize+barrier) ----
    uint4 pbH[4], pbC[4];
    #pragma unroll
    for (int kt = 0; kt < 4; ++kt){
      pbH[kt] = *(const uint4*)(WattQ + (((wv * 8 + kt) * 64 + lane) << 4));
      pbC[kt] = *(const uint4*)(WattQ + (((wv * 8 + 4 + kt) * 64 + lane) << 4));
    }

    // ---- quantize state to int8 with dynamic per-j scales (waves 0-7) ----
    if (tid < 512){
      const float mh = fmaxf(fmaxf(redH[jj * 4], redH[jj * 4 + 1]),
                             fmaxf(redH[jj * 4 + 2], redH[jj * 4 + 3])) + 1e-30f;
      const float mc = fmaxf(fmaxf(redC[jj * 4], redC[jj * 4 + 1]),
                             fmaxf(redC[jj * 4 + 2], redC[jj * 4 + 3])) + 1e-30f;
      hQ[jj][pp] = (s8)rintf(hcin[jj][pp]       * (127.f / mh));
      cQ[jj][pp] = (s8)rintf(hcin[jj][256 + pp] * (127.f / mc));
      if (pp == 0){ mS[jj] = mh; mS[2 + jj] = mc; }
    }
    __syncthreads();  // S0b: hQ/cQ/mS ready

    // ================= phase A: P1 only (all waves; short) =================
    {
      const int v = lane & 1;
      i32x4 accH = (i32x4){0, 0, 0, 0};
      i32x4 accC = (i32x4){0, 0, 0, 0};
      #pragma unroll
      for (int kt = 0; kt < 4; ++kt){
        const uint4 aH = *(const uint4*)&hQ[v][kt * 64 + q * 16];
        accH = mfma_i8(aH, pbH[kt], accH);
      }
      #pragma unroll
      for (int kt = 0; kt < 4; ++kt){
        const uint4 aC = *(const uint4*)&cQ[v][kt * 64 + q * 16];
        accC = mfma_i8(aC, pbC[kt], accC);
      }
      if (lane < 16){
        const float sc = w1s[wv * 16 + col];
        const float v0 = ((float)accH[0] * mS[0] + (float)accC[0] * mS[2]) * sc;
        const float v1 = ((float)accH[1] * mS[1] + (float)accC[1] * mS[3]) * sc;
        *(float2*)&hcpP[(wv * 16 + col) * 2] = make_float2(v0, v1);
      }
    }
    __syncthreads();  // S1: hcpP ready

    // ================= phase B: P2 (waves 0-3) || all gate tiles (waves 4-15) =================
    if (wv < 4){
      // P2 partial: wave wv covers h2 in [wv*32, wv*32+32); lane = s
      const int par = lane & 1;
      float sc = 0.f;
      #pragma unroll 4
      for (int h2 = wv * 32; h2 < wv * 32 + 32; ++h2){
        const u32 ee = *(const u32*)&encT[lane * ETS + 2 * h2];
        const float4 hp = *(const float4*)&hcpP[4 * h2];
        const float2 ww = *(const float2*)&w3L[2 * h2];
        const float a0v = bf2f(ee & 0xffff) + (par ? hp.y : hp.x);
        const float a1v = bf2f(ee >> 16)    + (par ? hp.w : hp.z);
        sc += ww.x * tanh_fast(a0v) + ww.y * tanh_fast(a1v);
      }
      scp[wv][lane] = sc;
    } else {
      // gate A-frags (both j; cheap LDS reads)
      uint4 aG0[4], aG1[4];
      #pragma unroll
      for (int kt = 0; kt < 4; ++kt){
        aG0[kt] = *(const uint4*)&hQ[0][kt * 64 + q * 16];
        aG1[kt] = *(const uint4*)&hQ[1][kt * 64 + q * 16];
      }
      const int u0 = gstart, u1 = gstart + gcnt;
      if (u0 < 64)
        gate_tiles(u0, (u1 < 64 ? u1 : 64), aG0, WhhQ, preSi[0], lane, col);
      if (u1 > 64)
        gate_tiles((u0 > 64 ? u0 : 64) - 64, u1 - 64, aG1, WhhQ + 262144, preSi[1], lane, col);
    }
    __syncthreads();  // S2: preS complete, scp ready

    // ================= softmax + ytil (waves 0-7, redundant) + LSTM update =================
    if (tid < 512){
      float sc = scp[0][lane] + scp[1][lane] + scp[2][lane] + scp[3][lane];
      float mx = sc;
      #pragma unroll
      for (int o = 32; o > 0; o >>= 1) mx = fmaxf(mx, __shfl_xor(mx, o, 64));
      const float e = __builtin_amdgcn_exp2f((sc - mx) * 1.44269504089f);
      float sm = e;
      #pragma unroll
      for (int o = 32; o > 0; o >>= 1) sm += __shfl_xor(sm, o, 64);
      const float a = e / sm;
      if (wv == 0){
        attwS[lane] = a;
        attw_acc[lane] += a;
      }
      float yp = a * encFE[lane];
      yp = wave_sum(yp);
      const float ytil = yp + yS[t] * feY + sS[t] * feS + feB;

      const float mh = mS[jj];
      const float pi = (float)preSi[jj][pp]       * (mh * c4i) + ytil * wvg_i + gb_i;
      const float pf = (float)preSi[jj][pp + 256] * (mh * c4f) + ytil * wvg_f + gb_f;
      const float pg = (float)preSi[jj][pp + 512] * (mh * c4g) + ytil * wvg_g + gb_g;
      const float po = (float)preSi[jj][pp + 768] * (mh * c4o) + ytil * wvg_o + gb_o;
      const float cold = hcin[jj][256 + pp];
      const float cnew = sigm(pf) * cold + sigm(pi) * tanh_fast(pg);
      const float hnew = sigm(po) * tanh_fast(cnew);
      hcin[jj][256 + pp] = cnew;
      hcin[jj][pp]       = hnew;
      float ah = fabsf(hnew), ac = fabsf(cnew);
      #pragma unroll
      for (int o = 32; o > 0; o >>= 1){
        ah = fmaxf(ah, __shfl_xor(ah, o, 64));
        ac = fmaxf(ac, __shfl_xor(ac, o, 64));
      }
      if (lane == 0){ redH[wv] = ah; redC[wv] = ac; }
    }
    __syncthreads();  // S0: state + maxima ready for next step
  }

  // ---- outputs ----
  if (tid < 64) out[b * 64 + tid] = attw_acc[tid] * 0.015625f;  // /64

  // final context from last step's attw
  if (tid < 512){
    float ca = 0.f;
    #pragma unroll 8
    for (int s = 0; s < 64; ++s)
      ca += attwS[s] * bf2f(encLDS[s * 512 + tid]);
    ctx[tid] = ca;
  }
  __syncthreads();

  if (tid < 256){
    float part = hcin[0][tid]     * fcfw[tid]
               + ctx[tid]         * fcfw[256 + tid]
               + ctx[256 + tid]   * fcfw[512 + tid];
    part = wave_sum(part);
    if (lane == 0) red[wv] = part;
  }
  __syncthreads();
  if (tid == 0) out[16384 + b] = red[0] + red[1] + red[2] + red[3] + fcfb[0];
}

// ---------------- launch ----------------
extern "C" void kernel_launch(void* const* d_in, const int* in_sizes, int n_in,
                              void* d_out, int out_size, void* d_ws, size_t ws_size,
                              hipStream_t stream)
{
  const float* enc  = (const float*)d_in[0];
  const float* yh   = (const float*)d_in[1];
  const float* sp   = (const float*)d_in[2];
  const float* h0   = (const float*)d_in[3];
  const float* c0   = (const float*)d_in[4];
  const float* w1   = (const float*)d_in[5];
  const float* b1   = (const float*)d_in[6];
  const float* w2   = (const float*)d_in[7];
  const float* b2   = (const float*)d_in[8];
  const float* w3   = (const float*)d_in[9];
  const float* wihf = (const float*)d_in[11];
  const float* whhf = (const float*)d_in[12];
  const float* bihf = (const float*)d_in[13];
  const float* bhhf = (const float*)d_in[14];
  const float* wihb = (const float*)d_in[15];
  const float* whhb = (const float*)d_in[16];
  const float* bihb = (const float*)d_in[17];
  const float* bhhb = (const float*)d_in[18];
  const float* fcw1 = (const float*)d_in[19];
  const float* fcb1 = (const float*)d_in[20];
  const float* fcw2 = (const float*)d_in[21];
  const float* fcb2 = (const float*)d_in[22];
  const float* fcfw = (const float*)d_in[23];
  const float* fcfb = (const float*)d_in[24];

  char* ws = (char*)d_ws;
  s8*    WattQ = (s8*)(ws);
  u16*   WencB = (u16*)(ws + 131072);
  s8*    WhhQ  = (s8*)(ws + 393216);
  float* beff  = (float*)(ws + 917504);
  float* gbias = (float*)(ws + 918528);
  float* cmAtt = (float*)(ws + 926720);
  float* cmWhh = (float*)(ws + 927744);
  float* fcE   = (float*)(ws + 935936);
  float* out   = (float*)d_out;

  prep_attn<<<dim3(256), dim3(256), 0, stream>>>(w1, b1, w2, b2, WattQ, WencB, beff, cmAtt);
  prep_whh_i8<<<dim3(8), dim3(256), 0, stream>>>(whhf, whhb, bihf, bhhf, bihb, bhhb,
                                                 WhhQ, gbias, cmWhh);
  prep_fc<<<dim3(1), dim3(256), 0, stream>>>(fcw1, fcb1, fcw2, fcb2, fcE);
  decoder_main<<<dim3(256), dim3(1024), 0, stream>>>(
      enc, yh, sp, h0, c0, w3, wihf, wihb, fcfw, fcfb,
      WattQ, WencB, WhhQ, beff, gbias, cmAtt, cmWhh, fcE, out);
}

// Round 11
// 691.606 us; speedup vs baseline: 1.2175x; 1.2175x over previous
//
#include <hip/hip_runtime.h>
#include <stdint.h>

typedef unsigned short u16;
typedef unsigned int   u32;
typedef signed char    s8;

typedef __bf16 bf16x8 __attribute__((ext_vector_type(8)));
typedef float  f32x4  __attribute__((ext_vector_type(4)));
typedef int    i32x4  __attribute__((ext_vector_type(4)));

// Sizes: B=256, T=64, H=256, M2=512, gates=1024
// ws layout (bytes):
//   WattQ  i8 B-frag [nt<16][kt<8][lane<64][i<16] : off 0,      sz 131072
//   WencB  bf16 B-frag (K=32 tiles)               : off 131072, sz 262144
//   WhhQ   i8 B-frag [j][nt<64][kt<4][lane][i]    : off 393216, sz 524288
//   beff   f32 [256]                              : off 917504
//   gbias  f32 [2][1024]                          : off 918528
//   cmAtt  f32 [256]                              : off 926720
//   cmWhh  f32 [2048]                             : off 927744
//   fcE    f32 [515]                              : off 935936

__device__ __forceinline__ float bf2f(u16 v){ return __uint_as_float(((u32)v) << 16); }
__device__ __forceinline__ u16 f2bf(float f){
  u32 u = __float_as_uint(f);
  u += 0x7fffu + ((u >> 16) & 1u);
  return (u16)(u >> 16);
}
__device__ __forceinline__ u32 pk2(float a, float b){
  return (u32)f2bf(a) | (((u32)f2bf(b)) << 16);
}
__device__ __forceinline__ float wave_sum(float v){
  #pragma unroll
  for (int o = 32; o > 0; o >>= 1) v += __shfl_xor(v, o, 64);
  return v;
}
__device__ __forceinline__ float tanh_fast(float x){
  float e = __builtin_amdgcn_exp2f(x * 2.88539008178f); // 2*log2(e)
  return 1.0f - 2.0f * __builtin_amdgcn_rcpf(1.0f + e);
}
__device__ __forceinline__ float sigm(float x){
  float e = __builtin_amdgcn_exp2f(-x * 1.44269504089f);
  return __builtin_amdgcn_rcpf(1.0f + e);
}
__device__ __forceinline__ f32x4 mfma16(bf16x8 a, bf16x8 b, f32x4 c){
  return __builtin_amdgcn_mfma_f32_16x16x32_bf16(a, b, c, 0, 0, 0);
}
__device__ __forceinline__ i32x4 mfma_i8(uint4 a, uint4 b, i32x4 c){
  return __builtin_amdgcn_mfma_i32_16x16x64_i8(
      __builtin_bit_cast(i32x4, a), __builtin_bit_cast(i32x4, b), c, 0, 0, 0);
}
// bf16 B-frag index (16x16x32): lane = ((k>>3)&3)*16 + (n&15), i = k&7
__device__ __forceinline__ size_t bfrag_idx(int n, int k, int KS){
  return ((size_t)((n >> 4) * KS + (k >> 5)) * 64 + ((k >> 3) & 3) * 16 + (n & 15)) * 8 + (k & 7);
}
// i8 B-frag index (16x16x64): lane = ((k>>4)&3)*16 + (n&15), i = k&15; KS = K/64
__device__ __forceinline__ size_t bq_idx(int n, int k, int KS){
  return ((size_t)((n >> 4) * KS + (k >> 6)) * 64 + ((k >> 4) & 3) * 16 + (n & 15)) * 16 + (k & 15);
}

#define ETS 258   // encT padded stride (u16); dword stride 129 (odd) -> conflict-free

// ---------------- prep kernels (R7, verified) ----------------

__global__ __launch_bounds__(256) void prep_attn(
    const float* __restrict__ w1, const float* __restrict__ b1,
    const float* __restrict__ w2, const float* __restrict__ b2,
    s8* __restrict__ WattQ, u16* __restrict__ WencB,
    float* __restrict__ beff, float* __restrict__ cmAtt)
{
  const int h = blockIdx.x, tid = threadIdx.x;
  __shared__ float w2row[256];
  __shared__ float red[256];
  w2row[tid] = w2[h * 256 + tid];
  __syncthreads();
  float acc0 = 0.f, acc1 = 0.f, acc2 = 0.f, acc3 = 0.f;
  for (int m = 0; m < 256; ++m){
    const float wm = w2row[m];
    const float* r = w1 + m * 1024 + tid;
    acc0 += wm * r[0];
    acc1 += wm * r[256];
    acc2 += wm * r[512];
    acc3 += wm * r[768];
  }
  WencB[bfrag_idx(h, tid,       16)] = f2bf(acc2);
  WencB[bfrag_idx(h, tid + 256, 16)] = f2bf(acc3);
  red[tid] = fmaxf(fabsf(acc0), fabsf(acc1));
  __syncthreads();
  for (int s = 128; s > 0; s >>= 1){
    if (tid < s) red[tid] = fmaxf(red[tid], red[tid + s]);
    __syncthreads();
  }
  const float cm = red[0] + 1e-30f;
  const float s127 = 127.f / cm;
  WattQ[bq_idx(h, tid,       8)] = (s8)rintf(acc0 * s127);
  WattQ[bq_idx(h, tid + 256, 8)] = (s8)rintf(acc1 * s127);
  if (tid == 0) cmAtt[h] = cm;
  __syncthreads();
  red[tid] = w2row[tid] * b1[tid];
  __syncthreads();
  for (int s = 128; s > 0; s >>= 1){
    if (tid < s) red[tid] += red[tid + s];
    __syncthreads();
  }
  if (tid == 0) beff[h] = red[0] + b2[h];
}

__global__ __launch_bounds__(256) void prep_whh_i8(
    const float* __restrict__ whhf, const float* __restrict__ whhb,
    const float* __restrict__ bihf, const float* __restrict__ bhhf,
    const float* __restrict__ bihb, const float* __restrict__ bhhb,
    s8* __restrict__ WhhQ, float* __restrict__ gbias, float* __restrict__ cmWhh)
{
  const int col = blockIdx.x * 256 + threadIdx.x;  // < 2048
  const int j = col >> 10, n = col & 1023;
  const float* w = j ? whhb : whhf;
  const float* r = w + n * 256;
  float cm = 0.f;
  for (int k = 0; k < 256; ++k) cm = fmaxf(cm, fabsf(r[k]));
  cm += 1e-30f;
  cmWhh[col] = cm;
  const float s127 = 127.f / cm;
  s8* dst = WhhQ + (size_t)j * 262144;
  for (int k = 0; k < 256; ++k)
    dst[bq_idx(n, k, 4)] = (s8)rintf(r[k] * s127);
  gbias[col] = j ? (bihb[n] + bhhb[n]) : (bihf[n] + bhhf[n]);
}

__global__ __launch_bounds__(256) void prep_fc(
    const float* __restrict__ fcw1, const float* __restrict__ fcb1,
    const float* __restrict__ fcw2, const float* __restrict__ fcb2,
    float* __restrict__ fcE)
{
  const int tid = threadIdx.x;
  __shared__ float w2s[256];
  __shared__ float red[256];
  w2s[tid] = fcw2[tid];
  __syncthreads();
  for (int m = tid; m < 514; m += 256){
    float a = 0.f;
    for (int hh = 0; hh < 256; ++hh) a += w2s[hh] * fcw1[hh * 514 + m];
    fcE[m] = a;
  }
  red[tid] = w2s[tid] * fcb1[tid];
  __syncthreads();
  for (int s = 128; s > 0; s >>= 1){
    if (tid < s) red[tid] += red[tid + s];
    __syncthreads();
  }
  if (tid == 0) fcE[514] = red[0] + fcb2[0];
}

// ---- gate tiles: nt in [nt0, ntEnd), single j. Pair-batched (8 loads in
// flight) + single remainder. Pairs are the empirically spill-free width. ----
__device__ __forceinline__ void gate_pair_loop(int nt0, int ntEnd,
    const uint4 (&aG)[4], const s8* __restrict__ wbJ, int* __restrict__ preSj,
    int lane, int col)
{
  int nt = nt0;
  #pragma unroll 1
  for (; nt + 1 < ntEnd; nt += 2){
    uint4 gb[8];
    #pragma unroll
    for (int kt = 0; kt < 4; ++kt){
      gb[kt]     = *(const uint4*)(wbJ + (((nt * 4 + kt) * 64 + lane) << 4));
      gb[4 + kt] = *(const uint4*)(wbJ + ((((nt + 1) * 4 + kt) * 64 + lane) << 4));
    }
    i32x4 g0 = (i32x4){0,0,0,0}, g1 = (i32x4){0,0,0,0};
    #pragma unroll
    for (int kt = 0; kt < 4; ++kt){
      g0 = mfma_i8(aG[kt], gb[kt],     g0);
      g1 = mfma_i8(aG[kt], gb[4 + kt], g1);
    }
    if (lane < 16){
      preSj[nt * 16 + col]       = g0[0];
      preSj[(nt + 1) * 16 + col] = g1[0];
    }
  }
  if (nt < ntEnd){
    i32x4 g0 = (i32x4){0,0,0,0};
    #pragma unroll
    for (int kt = 0; kt < 4; ++kt){
      const uint4 b0 = *(const uint4*)(wbJ + (((nt * 4 + kt) * 64 + lane) << 4));
      g0 = mfma_i8(aG[kt], b0, g0);
    }
    if (lane < 16) preSj[nt * 16 + col] = g0[0];
  }
}

// ---------------- main kernel: 1024 threads (16 waves) per batch element ----------------
__global__ __launch_bounds__(1024, 4) void decoder_main(
    const float* __restrict__ enc,   const float* __restrict__ yhist,
    const float* __restrict__ speed, const float* __restrict__ h0,
    const float* __restrict__ c0,    const float* __restrict__ aw3,
    const float* __restrict__ wihf,  const float* __restrict__ wihb,
    const float* __restrict__ fcfw,  const float* __restrict__ fcfb,
    const s8* __restrict__ WattQ,    const u16* __restrict__ WencB,
    const s8* __restrict__ WhhQ,     const float* __restrict__ beff,
    const float* __restrict__ gbias, const float* __restrict__ cmAtt,
    const float* __restrict__ cmWhh, const float* __restrict__ fcE,
    float* __restrict__ out)
{
  const int b = blockIdx.x, tid = threadIdx.x;
  const int lane = tid & 63, wv = tid >> 6;   // wv < 16
  const int q = lane >> 4, col = lane & 15;

  __shared__ float hcin[2][512];               // fp32 state: [j][k<256]=h, [256..512)=c
  __shared__ alignas(16) s8 hQ[2][256];        // int8 quantized h (per-step)
  __shared__ alignas(16) s8 cQ[2][256];        // int8 quantized c
  __shared__ alignas(16) u16 encT[64 * ETS];   // enc attention term, padded stride
  __shared__ alignas(16) u16 encLDS[64 * 512]; // raw enc (bf16), prologue+epilogue
  __shared__ alignas(16) float hcpP[512];      // attention projection, [h][v] pairs
  __shared__ alignas(16) float w3L[256];
  __shared__ float w1s[256];                   // cmAtt/127^2
  __shared__ alignas(16) float4 lstmC[3][512]; // LSTM per-thread constants (wih / gbias / c4)
  __shared__ float ytadd[64];                  // y*feY + s*feS + feB per step
  __shared__ float encFE[64];
  __shared__ float attwS[64];
  __shared__ float attw_acc[64];
  __shared__ float scp[4][64];                 // P2 h-quarter partials
  __shared__ float red[16];
  __shared__ float redH[8], redC[8];           // per-wave |h|,|c| maxima (waves 0..7)
  __shared__ float mS[4];                      // m_h[0..1], m_c[0..1]
  __shared__ int   preSi[2][1024];             // raw i32 gate dots from MFMA
  __shared__ float ctx[512];

  // ---- init state + |h0|,|c0| wave maxima + staged constants ----
  if (tid < 512){
    const int j = tid >> 8, p = tid & 255;
    const float hv = h0[j * 65536 + b * 256 + p];
    const float cv = c0[j * 65536 + b * 256 + p];
    hcin[j][p]       = hv;
    hcin[j][256 + p] = cv;
    float ah = fabsf(hv), ac = fabsf(cv);
    #pragma unroll
    for (int o = 32; o > 0; o >>= 1){
      ah = fmaxf(ah, __shfl_xor(ah, o, 64));
      ac = fmaxf(ac, __shfl_xor(ac, o, 64));
    }
    if (lane == 0){ redH[wv] = ah; redC[wv] = ac; }
    // LSTM constants -> LDS (frees ~15 pinned VGPRs in the hot loop)
    const float* wihJ = j ? wihb : wihf;
    lstmC[0][tid] = make_float4(wihJ[p], wihJ[p + 256], wihJ[p + 512], wihJ[p + 768]);
    lstmC[1][tid] = make_float4(gbias[j * 1024 + p],       gbias[j * 1024 + p + 256],
                                gbias[j * 1024 + p + 512], gbias[j * 1024 + p + 768]);
    lstmC[2][tid] = make_float4(cmWhh[j * 1024 + p]       * (1.f / 16129.f),
                                cmWhh[j * 1024 + p + 256] * (1.f / 16129.f),
                                cmWhh[j * 1024 + p + 512] * (1.f / 16129.f),
                                cmWhh[j * 1024 + p + 768] * (1.f / 16129.f));
  }
  if (tid < 64){
    attw_acc[tid] = 0.f;
    ytadd[tid] = yhist[b * 64 + tid] * fcE[512] + speed[b * 64 + tid] * fcE[513] + fcE[514];
  }
  if (tid < 256){
    w3L[tid] = aw3[tid];
    w1s[tid] = cmAtt[tid] * (1.f / 16129.f);
  }

  const float* encB = enc + (size_t)b * 32768;

  // ---- prologue: encT[s][h] = enc[b,s,:].WencB + beff (bf16 MFMA GEMM, M=64,K=512,N=256)
  {
    const int mt = wv >> 2, g = wv & 3;
    const int s = mt * 16 + col;
    f32x4 acc[4];
    #pragma unroll
    for (int tt = 0; tt < 4; ++tt) acc[tt] = (f32x4){0.f, 0.f, 0.f, 0.f};
    #pragma unroll 1
    for (int ks = 0; ks < 16; ++ks){
      const float* ap = encB + s * 512 + ks * 32 + q * 8;
      const float4 e0 = *(const float4*)ap;
      const float4 e1 = *(const float4*)(ap + 4);
      uint4 af;
      af.x = pk2(e0.x, e0.y); af.y = pk2(e0.z, e0.w);
      af.z = pk2(e1.x, e1.y); af.w = pk2(e1.z, e1.w);
      if (g == 0) *(uint4*)&encLDS[s * 512 + ks * 32 + q * 8] = af;
      const bf16x8 a = __builtin_bit_cast(bf16x8, af);
      #pragma unroll
      for (int tt = 0; tt < 4; ++tt){
        const int nt = g * 4 + tt;
        const uint4 bw = *(const uint4*)(WencB + (((nt * 16 + ks) * 64 + lane) << 3));
        acc[tt] = mfma16(a, __builtin_bit_cast(bf16x8, bw), acc[tt]);
      }
    }
    #pragma unroll
    for (int tt = 0; tt < 4; ++tt){
      const int nt = g * 4 + tt;
      const float bv = beff[nt * 16 + col];
      #pragma unroll
      for (int r = 0; r < 4; ++r)
        encT[(mt * 16 + q * 4 + r) * ETS + nt * 16 + col] = f2bf(acc[tt][r] + bv);
    }
  }
  __syncthreads();  // encLDS ready

  // ---- encFE[s] = sum_m bf16(enc[s,m]) * fcE[m]
  {
    const float4 f0 = *(const float4*)(fcE + lane * 8);
    const float4 f1 = *(const float4*)(fcE + lane * 8 + 4);
    #pragma unroll
    for (int r = 0; r < 4; ++r){
      const int s = wv * 4 + r;
      const uint4 ev = *(const uint4*)&encLDS[s * 512 + lane * 8];
      float p = bf2f(ev.x & 0xffff) * f0.x + bf2f(ev.x >> 16) * f0.y
              + bf2f(ev.y & 0xffff) * f0.z + bf2f(ev.y >> 16) * f0.w
              + bf2f(ev.z & 0xffff) * f1.x + bf2f(ev.z >> 16) * f1.y
              + bf2f(ev.w & 0xffff) * f1.z + bf2f(ev.w >> 16) * f1.w;
      p = wave_sum(p);
      if (lane == 0) encFE[s] = p;
    }
  }

  // ---- update-phase ids (tid<512) ----
  const int jj = (tid >> 8) & 1, pp = tid & 255;

  // ---- gate tile assignment: SINGLE j per wave (one aG[4] -> fewer live regs)
  // waves 0-3: 4 j0-tiles (phase A only; P2 in phase B)
  // waves 4-9: 8 j0-tiles; waves 10-13: 11 j1-tiles; waves 14-15: 10 j1-tiles.
  int tbase, tcnt, gj;
  if (wv < 4)       { tbase = wv * 4;             tcnt = 4;  gj = 0; }
  else if (wv < 10) { tbase = 16 + (wv - 4) * 8;  tcnt = 8;  gj = 0; }
  else if (wv < 14) { tbase = (wv - 10) * 11;     tcnt = 11; gj = 1; }
  else              { tbase = 44 + (wv - 14) * 10; tcnt = 10; gj = 1; }
  const s8* wbJ = WhhQ + (size_t)gj * 262144;
  int* preSj = preSi[gj];

  __syncthreads();  // init/encFE visible

  // ---- 64 sequential decode steps ----
  #pragma unroll 1
  for (int t = 0; t < 64; ++t){
    // ---- prefetch P1 B-frags (state-independent; overlap quantize+barrier) ----
    uint4 pbH[4], pbC[4];
    #pragma unroll
    for (int kt = 0; kt < 4; ++kt){
      pbH[kt] = *(const uint4*)(WattQ + (((wv * 8 + kt) * 64 + lane) << 4));
      pbC[kt] = *(const uint4*)(WattQ + (((wv * 8 + 4 + kt) * 64 + lane) << 4));
    }

    // ---- quantize state to int8 with dynamic per-j scales (waves 0-7) ----
    if (tid < 512){
      const float mh = fmaxf(fmaxf(redH[jj * 4], redH[jj * 4 + 1]),
                             fmaxf(redH[jj * 4 + 2], redH[jj * 4 + 3])) + 1e-30f;
      const float mc = fmaxf(fmaxf(redC[jj * 4], redC[jj * 4 + 1]),
                             fmaxf(redC[jj * 4 + 2], redC[jj * 4 + 3])) + 1e-30f;
      hQ[jj][pp] = (s8)rintf(hcin[jj][pp]       * (127.f / mh));
      cQ[jj][pp] = (s8)rintf(hcin[jj][256 + pp] * (127.f / mc));
      if (pp == 0){ mS[jj] = mh; mS[2 + jj] = mc; }
    }
    __syncthreads();  // S0b: hQ/cQ/mS ready

    // ================= phase A: P1 + first 4 gate tiles per wave =================
    {
      const int v = lane & 1;
      i32x4 accH = (i32x4){0, 0, 0, 0};
      i32x4 accC = (i32x4){0, 0, 0, 0};
      #pragma unroll
      for (int kt = 0; kt < 4; ++kt){
        const uint4 aH = *(const uint4*)&hQ[v][kt * 64 + q * 16];
        accH = mfma_i8(aH, pbH[kt], accH);
      }
      #pragma unroll
      for (int kt = 0; kt < 4; ++kt){
        const uint4 aC = *(const uint4*)&cQ[v][kt * 64 + q * 16];
        accC = mfma_i8(aC, pbC[kt], accC);
      }
      if (lane < 16){
        const float sc = w1s[wv * 16 + col];
        const float v0 = ((float)accH[0] * mS[0] + (float)accC[0] * mS[2]) * sc;
        const float v1 = ((float)accH[1] * mS[1] + (float)accC[1] * mS[3]) * sc;
        *(float2*)&hcpP[(wv * 16 + col) * 2] = make_float2(v0, v1);
      }
    }
    // single-j gate A-frag
    uint4 aG[4];
    #pragma unroll
    for (int kt = 0; kt < 4; ++kt)
      aG[kt] = *(const uint4*)&hQ[gj][kt * 64 + q * 16];
    // phase-A gate tiles: [tbase, tbase+4)
    gate_pair_loop(tbase, tbase + 4, aG, wbJ, preSj, lane, col);
    __syncthreads();  // S1: hcpP + phase-a preS ready

    // ================= phase B =================
    if (wv < 4){
      // P2 partial: wave wv covers h2 in [wv*32, wv*32+32); lane = s
      const int par = lane & 1;
      float sc = 0.f;
      #pragma unroll 4
      for (int h2 = wv * 32; h2 < wv * 32 + 32; ++h2){
        const u32 ee = *(const u32*)&encT[lane * ETS + 2 * h2];
        const float4 hp = *(const float4*)&hcpP[4 * h2];
        const float2 ww = *(const float2*)&w3L[2 * h2];
        const float a0v = bf2f(ee & 0xffff) + (par ? hp.y : hp.x);
        const float a1v = bf2f(ee >> 16)    + (par ? hp.w : hp.z);
        sc += ww.x * tanh_fast(a0v) + ww.y * tanh_fast(a1v);
      }
      scp[wv][lane] = sc;
    } else {
      // remaining gate tiles: [tbase+4, tbase+tcnt)
      gate_pair_loop(tbase + 4, tbase + tcnt, aG, wbJ, preSj, lane, col);
    }
    __syncthreads();  // S2: preS complete, scp ready

    // ================= softmax + ytil (waves 0-7, redundant) + LSTM update =================
    if (tid < 512){
      float sc = scp[0][lane] + scp[1][lane] + scp[2][lane] + scp[3][lane];
      float mx = sc;
      #pragma unroll
      for (int o = 32; o > 0; o >>= 1) mx = fmaxf(mx, __shfl_xor(mx, o, 64));
      const float e = __builtin_amdgcn_exp2f((sc - mx) * 1.44269504089f);
      float sm = e;
      #pragma unroll
      for (int o = 32; o > 0; o >>= 1) sm += __shfl_xor(sm, o, 64);
      const float a = e / sm;
      if (wv == 0){
        attwS[lane] = a;
        attw_acc[lane] += a;
      }
      float yp = a * encFE[lane];
      yp = wave_sum(yp);
      const float ytil = yp + ytadd[t];

      const float4 Wv = lstmC[0][tid];
      const float4 Gb = lstmC[1][tid];
      const float4 C4 = lstmC[2][tid];
      const float mh = mS[jj];
      const float pi = (float)preSi[jj][pp]       * (mh * C4.x) + ytil * Wv.x + Gb.x;
      const float pf = (float)preSi[jj][pp + 256] * (mh * C4.y) + ytil * Wv.y + Gb.y;
      const float pg = (float)preSi[jj][pp + 512] * (mh * C4.z) + ytil * Wv.z + Gb.z;
      const float po = (float)preSi[jj][pp + 768] * (mh * C4.w) + ytil * Wv.w + Gb.w;
      const float cold = hcin[jj][256 + pp];
      const float cnew = sigm(pf) * cold + sigm(pi) * tanh_fast(pg);
      const float hnew = sigm(po) * tanh_fast(cnew);
      hcin[jj][256 + pp] = cnew;
      hcin[jj][pp]       = hnew;
      float ah = fabsf(hnew), ac = fabsf(cnew);
      #pragma unroll
      for (int o = 32; o > 0; o >>= 1){
        ah = fmaxf(ah, __shfl_xor(ah, o, 64));
        ac = fmaxf(ac, __shfl_xor(ac, o, 64));
      }
      if (lane == 0){ redH[wv] = ah; redC[wv] = ac; }
    }
    __syncthreads();  // S0: state + maxima ready for next step
  }

  // ---- outputs ----
  if (tid < 64) out[b * 64 + tid] = attw_acc[tid] * 0.015625f;  // /64

  // final context from last step's attw
  if (tid < 512){
    float ca = 0.f;
    #pragma unroll 8
    for (int s = 0; s < 64; ++s)
      ca += attwS[s] * bf2f(encLDS[s * 512 + tid]);
    ctx[tid] = ca;
  }
  __syncthreads();

  if (tid < 256){
    float part = hcin[0][tid]     * fcfw[tid]
               + ctx[tid]         * fcfw[256 + tid]
               + ctx[256 + tid]   * fcfw[512 + tid];
    part = wave_sum(part);
    if (lane == 0) red[wv] = part;
  }
  __syncthreads();
  if (tid == 0) out[16384 + b] = red[0] + red[1] + red[2] + red[3] + fcfb[0];
}

// ---------------- launch ----------------
extern "C" void kernel_launch(void* const* d_in, const int* in_sizes, int n_in,
                              void* d_out, int out_size, void* d_ws, size_t ws_size,
                              hipStream_t stream)
{
  const float* enc  = (const float*)d_in[0];
  const float* yh   = (const float*)d_in[1];
  const float* sp   = (const float*)d_in[2];
  const float* h0   = (const float*)d_in[3];
  const float* c0   = (const float*)d_in[4];
  const float* w1   = (const float*)d_in[5];
  const float* b1   = (const float*)d_in[6];
  const float* w2   = (const float*)d_in[7];
  const float* b2   = (const float*)d_in[8];
  const float* w3   = (const float*)d_in[9];
  const float* wihf = (const float*)d_in[11];
  const float* whhf = (const float*)d_in[12];
  const float* bihf = (const float*)d_in[13];
  const float* bhhf = (const float*)d_in[14];
  const float* wihb = (const float*)d_in[15];
  const float* whhb = (const float*)d_in[16];
  const float* bihb = (const float*)d_in[17];
  const float* bhhb = (const float*)d_in[18];
  const float* fcw1 = (const float*)d_in[19];
  const float* fcb1 = (const float*)d_in[20];
  const float* fcw2 = (const float*)d_in[21];
  const float* fcb2 = (const float*)d_in[22];
  const float* fcfw = (const float*)d_in[23];
  const float* fcfb = (const float*)d_in[24];

  char* ws = (char*)d_ws;
  s8*    WattQ = (s8*)(ws);
  u16*   WencB = (u16*)(ws + 131072);
  s8*    WhhQ  = (s8*)(ws + 393216);
  float* beff  = (float*)(ws + 917504);
  float* gbias = (float*)(ws + 918528);
  float* cmAtt = (float*)(ws + 926720);
  float* cmWhh = (float*)(ws + 927744);
  float* fcE   = (float*)(ws + 935936);
  float* out   = (float*)d_out;

  prep_attn<<<dim3(256), dim3(256), 0, stream>>>(w1, b1, w2, b2, WattQ, WencB, beff, cmAtt);
  prep_whh_i8<<<dim3(8), dim3(256), 0, stream>>>(whhf, whhb, bihf, bhhf, bihb, bhhb,
                                                 WhhQ, gbias, cmWhh);
  prep_fc<<<dim3(1), dim3(256), 0, stream>>>(fcw1, fcb1, fcw2, fcb2, fcE);
  decoder_main<<<dim3(256), dim3(1024), 0, stream>>>(
      enc, yh, sp, h0, c0, w3, wihf, wihb, fcfw, fcfb,
      WattQ, WencB, WhhQ, beff, gbias, cmAtt, cmWhh, fcE, out);
}